// Round 3
// baseline (621.234 us; speedup 1.0000x reference)
//
#include <hip/hip_runtime.h>

typedef unsigned int u32;

#define NB 80
#define TPB2 256

namespace {
// ws layout (float offsets)
constexpr int OX_IMG = 0;                       // [13][36][768] x-img per depth (0=input)
constexpr int OX_TXT = 359424;                  // [13][36][512]
constexpr int OH     = 599040;                  // [36][160] hidden
constexpr int OSP    = 604800;                  // [36][80][2] LN-stat partials
constexpr int OCIMG  = 610560;                  // [36][768]
constexpr int OCTXT  = 638208;                  // [36][512]
constexpr int OBAR   = 656640;                  // 32 ints (barrier counters)
}

__device__ __forceinline__ float gelu_f(float x) { return 0.5f * x * (1.0f + erff(x * 0.70710678118654752f)); }

struct P {
    const float *vpc, *vpm, *tpc, *tpm, *cpc, *cpi, *cpt;
    const float *lig, *lib, *ltg, *ltb;
    const float *iw1, *ib1, *iw2, *ib2;
    const float *tw1, *tb1, *tw2, *tb2;
    const float *ciw1, *cib1, *ciw2, *cib2;
    const float *ctw1, *ctb1, *ctw2, *ctb2;
    float* ws;
};

// Device-wide barrier: one dedicated counter per instance; counters zeroed by
// hipMemsetAsync before each launch. 80 blocks <= 256 CUs -> co-resident.
__device__ __forceinline__ void gbar(int* bar, int idx) {
    __syncthreads();
    if (threadIdx.x == 0) {
        __threadfence();  // release my global writes
        __hip_atomic_fetch_add(&bar[idx], 1, __ATOMIC_ACQ_REL, __HIP_MEMORY_SCOPE_AGENT);
        while (__hip_atomic_load(&bar[idx], __ATOMIC_ACQUIRE, __HIP_MEMORY_SCOPE_AGENT) < NB) {
            __builtin_amdgcn_s_sleep(2);
        }
        __threadfence();  // acquire others' writes
    }
    __syncthreads();
}

__global__ __launch_bounds__(TPB2, 1) void chain_kernel(P p) {
    __shared__ float smem[5504];
    const int tid = threadIdx.x;
    const int b = blockIdx.x;
    float* XI = p.ws + OX_IMG;
    float* XT = p.ws + OX_TXT;
    float* H  = p.ws + OH;
    float* SP = p.ws + OSP;
    int* bar  = (int*)(p.ws + OBAR);

    // ---------------- prologue ----------------
    if (b < 36) {
        const int v = b / 12, t = b % 12;
        const float* is = (v == 2) ? p.vpm : p.vpc;   // [12][768]
        const float* ts = (v == 1) ? p.tpm : p.tpc;   // [12][512]
        float s = 0.f, s2 = 0.f;
        for (int k = tid; k < 768; k += TPB2) { float x = is[t * 768 + k]; XI[b * 768 + k] = x; s += x; s2 += x * x; }
        for (int k = tid; k < 512; k += TPB2) { float x = ts[t * 512 + k]; XT[b * 512 + k] = x; s += x; s2 += x * x; }
        #pragma unroll
        for (int off = 32; off > 0; off >>= 1) { s += __shfl_down(s, off); s2 += __shfl_down(s2, off); }
        if ((tid & 63) == 0) { smem[tid >> 6] = s; smem[4 + (tid >> 6)] = s2; }
        __syncthreads();
        if (tid == 0) {
            float S = 0.f, S2 = 0.f;
            #pragma unroll
            for (int w = 0; w < 4; ++w) { S += smem[w]; S2 += smem[4 + w]; }
            SP[(b * 80 + 0) * 2 + 0] = S; SP[(b * 80 + 0) * 2 + 1] = S2;
        }
        for (int q = 1 + tid; q < 80; q += TPB2) { SP[(b * 80 + q) * 2 + 0] = 0.f; SP[(b * 80 + q) * 2 + 1] = 0.f; }
    } else if (b < 72) {
        // common-prompt MLP for row rr
        const int rr = b - 36, v = rr / 12, t = rr % 12;
        const float* cs = (v == 0) ? p.cpc : (v == 1) ? p.cpi : p.cpt;
        float* cx  = smem;         // [512]
        float* ph  = smem + 512;   // [4][64]
        float* hhl = smem + 768;   // [64]
        for (int k = tid; k < 512; k += TPB2) cx[k] = cs[t * 512 + k];
        __syncthreads();
        {
            const int o = tid & 63, kc = tid >> 6;        // 4 K-chunks of 128
            const int path = o >> 5, j = o & 31;
            const float* w = (path ? p.ctw1 : p.ciw1) + (size_t)(kc * 128) * 32 + j;
            float a = 0.f;
            #pragma unroll 4
            for (int i = 0; i < 128; ++i) { a += cx[kc * 128 + i] * (*w); w += 32; }
            ph[kc * 64 + o] = a;
        }
        __syncthreads();
        if (tid < 64) {
            const int path = tid >> 5, j = tid & 31;
            float a = (path ? p.ctb1 : p.cib1)[j];
            #pragma unroll
            for (int kc = 0; kc < 4; ++kc) a += ph[kc * 64 + tid];
            hhl[tid] = gelu_f(a);
        }
        __syncthreads();
        for (int o = tid; o < 1280; o += TPB2) {
            if (o < 768) {
                float a = p.cib2[o];
                #pragma unroll
                for (int k = 0; k < 32; ++k) a += hhl[k] * p.ciw2[k * 768 + o];
                p.ws[OCIMG + rr * 768 + o] = a;
            } else {
                const int oo = o - 768;
                float a = p.ctb2[oo];
                #pragma unroll
                for (int k = 0; k < 32; ++k) a += hhl[32 + k] * p.ctw2[k * 512 + oo];
                p.ws[OCTXT + rr * 512 + oo] = a;
            }
        }
    }
    gbar(bar, 0);

    // ---------------- depth chain ----------------
    for (int d = 0; d < 12; ++d) {
        // ---- Phase A: LN-fused GEMV1 (1280 -> 160), block owns 2 cols x 36 rows ----
        {
            const int path = (b >= 40);
            const int j0 = 2 * b - (path ? 80 : 0);
            const float* W1 = (path ? p.tw1 : p.iw1) + (size_t)d * 1280 * 80;
            const float* G  = (path ? p.ltg : p.lig) + d * 1280;
            const float* Bb = (path ? p.ltb : p.lib) + d * 1280;
            float* wl = smem;          // [1280][2]
            float* gl = smem + 2560;   // [1280]
            float* bl = smem + 3840;   // [1280]
            float* ml = smem + 5120;   // [36]
            float* rl = smem + 5156;   // [36]
            float* sred = smem + 5192; // [36][4][2]
            for (int i = tid; i < 1280; i += TPB2) {
                float2 wv = *reinterpret_cast<const float2*>(W1 + (size_t)i * 80 + j0);
                wl[2 * i] = wv.x; wl[2 * i + 1] = wv.y;
                gl[i] = G[i]; bl[i] = Bb[i];
            }
            if (tid < 144) {
                const int r = tid >> 2, q = tid & 3;
                const float2* sp = reinterpret_cast<const float2*>(SP + (size_t)(r * 80 + q * 20) * 2);
                float s = 0.f, s2 = 0.f;
                #pragma unroll 4
                for (int i = 0; i < 20; ++i) { float2 v2 = sp[i]; s += v2.x; s2 += v2.y; }
                sred[(r * 4 + q) * 2] = s; sred[(r * 4 + q) * 2 + 1] = s2;
            }
            __syncthreads();
            if (tid < 36) {
                float S  = sred[tid * 8 + 0] + sred[tid * 8 + 2] + sred[tid * 8 + 4] + sred[tid * 8 + 6];
                float S2 = sred[tid * 8 + 1] + sred[tid * 8 + 3] + sred[tid * 8 + 5] + sred[tid * 8 + 7];
                float mm = S * (1.0f / 1280.0f);
                float vv = S2 * (1.0f / 1280.0f) - mm * mm;
                ml[tid] = mm; rl[tid] = rsqrtf(vv + 1e-5f);
            }
            __syncthreads();
            const int wv = tid >> 6, lane = tid & 63;
            const float* xi = XI + (size_t)d * 36 * 768;
            const float* xt = XT + (size_t)d * 36 * 512;
            for (int rr = 0; rr < 9; ++rr) {
                const int r = wv + 4 * rr;
                const float mmm = ml[r], rrs = rl[r];
                float a0 = 0.f, a1 = 0.f;
                const float* xr = xi + (size_t)r * 768;
                #pragma unroll 4
                for (int i = 0; i < 12; ++i) {
                    const int k = lane + 64 * i;
                    float xl = (xr[k] - mmm) * rrs * gl[k] + bl[k];
                    a0 += xl * wl[2 * k]; a1 += xl * wl[2 * k + 1];
                }
                const float* xr2 = xt + (size_t)r * 512;
                #pragma unroll 4
                for (int i = 0; i < 8; ++i) {
                    const int k2 = lane + 64 * i, k = 768 + k2;
                    float xl = (xr2[k2] - mmm) * rrs * gl[k] + bl[k];
                    a0 += xl * wl[2 * k]; a1 += xl * wl[2 * k + 1];
                }
                #pragma unroll
                for (int off = 32; off > 0; off >>= 1) { a0 += __shfl_down(a0, off); a1 += __shfl_down(a1, off); }
                if (lane == 0) {
                    const float* B1 = (path ? p.tb1 : p.ib1) + d * 80;
                    H[r * 160 + 2 * b]     = gelu_f(a0 + B1[j0]);
                    H[r * 160 + 2 * b + 1] = gelu_f(a1 + B1[j0 + 1]);
                }
            }
        }
        gbar(bar, 1 + 2 * d);
        // ---- Phase B: GEMV2 (80 -> 1280), block owns 16 cols x 36 rows ----
        {
            const int C0 = 16 * b;
            const int path = (C0 >= 768);
            const int c0 = C0 - (path ? 768 : 0);
            const int Np = path ? 512 : 768;
            const float* W2 = (path ? p.tw2 : p.iw2) + (size_t)d * 80 * Np;
            float* Hl  = smem;         // [36][80]
            float* w2l = smem + 2880;  // [80][16]
            float* b2l = smem + 4160;  // [16]
            float* ot  = smem + 4176;  // [36][16]
            for (int i = tid; i < 2880; i += TPB2) {
                const int r = i / 80, k = i % 80;
                Hl[i] = H[r * 160 + path * 80 + k];
            }
            for (int i = tid; i < 1280; i += TPB2) {
                const int k = i >> 4, c = i & 15;
                w2l[i] = W2[(size_t)k * Np + c0 + c];
            }
            if (tid < 16) b2l[tid] = (path ? p.tb2 : p.ib2)[d * Np + c0 + tid];
            __syncthreads();
            float* Xout = path ? (XT + (size_t)(d + 1) * 36 * 512) : (XI + (size_t)(d + 1) * 36 * 768);
            for (int o = tid; o < 576; o += TPB2) {
                const int r = o >> 4, c = o & 15;
                float a = b2l[c];
                const float* hr = Hl + r * 80;
                const float* wc = w2l + c;
                #pragma unroll 8
                for (int k = 0; k < 80; ++k) a += hr[k] * wc[k * 16];
                Xout[(size_t)r * Np + c0 + c] = a;
                ot[o] = a;
            }
            __syncthreads();
            if (tid < 36) {
                float s = 0.f, s2 = 0.f;
                #pragma unroll
                for (int c = 0; c < 16; ++c) { float x = ot[tid * 16 + c]; s += x; s2 += x * x; }
                SP[(tid * 80 + b) * 2] = s; SP[(tid * 80 + b) * 2 + 1] = s2;
            }
        }
        if (d < 11) gbar(bar, 2 + 2 * d);
    }
}

// Broadcast/gather to the big f32 outputs, 4 elems (16 B) per thread-iteration.
__global__ __launch_bounds__(256) void emit_kernel(const int* __restrict__ mt,
                                                   const float* __restrict__ ws,
                                                   float* __restrict__ out) {
    constexpr unsigned int C0 = 512u * 24 * 192;       // img0  [512][24][768] /4
    constexpr unsigned int C1 = 512u * 24 * 128;       // txt0  [512][24][512] /4
    constexpr unsigned int C2 = 11u * 512 * 12 * 192;  // imgs  [11][512][12][768] /4
    constexpr unsigned int C3 = 11u * 512 * 12 * 128;  // txts  [11][512][12][512] /4
    constexpr unsigned int TOT = C0 + C1 + C2 + C3;
    const unsigned int stride = gridDim.x * blockDim.x;
    for (unsigned int c = blockIdx.x * blockDim.x + threadIdx.x; c < TOT; c += stride) {
        const float* src;
        if (c < C0) {
            unsigned int b = c / 4608u, r = c % 4608u;          // 24*192
            unsigned int tok = r / 192u, col = (r % 192u) * 4u;
            int v = mt[b];
            src = (tok < 12u) ? ws + OX_IMG + ((size_t)36 + v * 12 + tok) * 768 + col
                              : ws + OCIMG + ((size_t)v * 12 + (tok - 12u)) * 768 + col;
        } else if (c < C0 + C1) {
            unsigned int cc = c - C0;
            unsigned int b = cc / 3072u, r = cc % 3072u;        // 24*128
            unsigned int tok = r / 128u, col = (r % 128u) * 4u;
            int v = mt[b];
            src = (tok < 12u) ? ws + OX_TXT + ((size_t)36 + v * 12 + tok) * 512 + col
                              : ws + OCTXT + ((size_t)v * 12 + (tok - 12u)) * 512 + col;
        } else if (c < C0 + C1 + C2) {
            unsigned int cc = c - C0 - C1;
            unsigned int d = cc / 1179648u, r = cc % 1179648u;  // 512*12*192
            unsigned int b = r / 2304u, rr = r % 2304u;         // 12*192
            unsigned int tok = rr / 192u, col = (rr % 192u) * 4u;
            int v = mt[b];
            src = ws + OX_IMG + ((size_t)(d + 2) * 36 + v * 12 + tok) * 768 + col;
        } else {
            unsigned int cc = c - C0 - C1 - C2;
            unsigned int d = cc / 786432u, r = cc % 786432u;    // 512*12*128
            unsigned int b = r / 1536u, rr = r % 1536u;         // 12*128
            unsigned int tok = rr / 128u, col = (rr % 128u) * 4u;
            int v = mt[b];
            src = ws + OX_TXT + ((size_t)(d + 2) * 36 + v * 12 + tok) * 512 + col;
        }
        *reinterpret_cast<float4*>(out + (size_t)c * 4) = *reinterpret_cast<const float4*>(src);
    }
}

extern "C" void kernel_launch(void* const* d_in, const int* in_sizes, int n_in,
                              void* d_out, int out_size, void* d_ws, size_t ws_size,
                              hipStream_t stream) {
    const int* mt = (const int*)d_in[0];
    P p;
    p.vpc  = (const float*)d_in[1];
    p.vpm  = (const float*)d_in[2];
    p.tpc  = (const float*)d_in[3];
    p.tpm  = (const float*)d_in[4];
    p.cpc  = (const float*)d_in[5];
    p.cpi  = (const float*)d_in[6];
    p.cpt  = (const float*)d_in[7];
    p.lig  = (const float*)d_in[8];
    p.lib  = (const float*)d_in[9];
    p.ltg  = (const float*)d_in[10];
    p.ltb  = (const float*)d_in[11];
    p.iw1  = (const float*)d_in[12];
    p.ib1  = (const float*)d_in[13];
    p.iw2  = (const float*)d_in[14];
    p.ib2  = (const float*)d_in[15];
    p.tw1  = (const float*)d_in[16];
    p.tb1  = (const float*)d_in[17];
    p.tw2  = (const float*)d_in[18];
    p.tb2  = (const float*)d_in[19];
    p.ciw1 = (const float*)d_in[20];
    p.cib1 = (const float*)d_in[21];
    p.ciw2 = (const float*)d_in[22];
    p.cib2 = (const float*)d_in[23];
    p.ctw1 = (const float*)d_in[24];
    p.ctb1 = (const float*)d_in[25];
    p.ctw2 = (const float*)d_in[26];
    p.ctb2 = (const float*)d_in[27];
    p.ws   = (float*)d_ws;

    // zero the barrier counters (replay-safe)
    hipMemsetAsync((char*)d_ws + (size_t)OBAR * 4, 0, 32 * sizeof(int), stream);
    chain_kernel<<<dim3(NB), dim3(TPB2), 0, stream>>>(p);
    emit_kernel<<<dim3(4096), dim3(256), 0, stream>>>(mt, (const float*)d_ws, (float*)d_out);
}

// Round 4
// 216.123 us; speedup vs baseline: 2.8744x; 2.8744x over previous
//
#include <hip/hip_runtime.h>

typedef unsigned int u32;
typedef unsigned short u16;

#define TPB 640

namespace {
// packed-path ws layout (float offsets)
constexpr size_t F_WP1  = 0;         // bf16[12][1280][160]  (img80++txt80)  -> 1,228,800 f32 slots
constexpr size_t F_WP2  = 1228800;   // bf16[12][80][1280]   (img768++txt512)->   614,400 f32 slots
constexpr size_t F_XI_P = 1843200;   // f32 [12][36][768]
constexpr size_t F_XT_P = 2174976;   // f32 [12][36][512]
constexpr size_t F_CI_P = 2396160;   // f32 [36][768]
constexpr size_t F_CT_P = 2423808;   // f32 [36][512]
constexpr size_t F_END_P = 2442240;  // 9,768,960 bytes needed
// fallback (f32 weights read in place) ws layout
constexpr size_t F_XI_U = 0;
constexpr size_t F_XT_U = 331776;
constexpr size_t F_CI_U = 552960;
constexpr size_t F_CT_U = 580608;
}

__device__ __forceinline__ float bflo(u32 u) { return __uint_as_float(u << 16); }
__device__ __forceinline__ float bfhi(u32 u) { return __uint_as_float(u & 0xffff0000u); }
__device__ __forceinline__ float gelu_f(float x) { return 0.5f * x * (1.0f + erff(x * 0.70710678118654752f)); }
__device__ __forceinline__ u16 f2bf(float f) {
    u32 u = __float_as_uint(f);
    u += 0x7fffu + ((u >> 16) & 1u);
    return (u16)(u >> 16);
}

struct P {
    const float *vpc, *vpm, *tpc, *tpm, *cpc, *cpi, *cpt;
    const float *lig, *lib, *ltg, *ltb;
    const float *iw1, *ib1, *iw2, *ib2;
    const float *tw1, *tb1, *tw2, *tb2;
    const float *ciw1, *cib1, *ciw2, *cib2;
    const float *ctw1, *ctb1, *ctw2, *ctb2;
    const u16 *wp1, *wp2;              // packed bf16 weights (PACKED=1)
    float *xi, *xt, *cimg, *ctxt;      // per-depth x state + common outputs
};

// Pack W1 -> bf16 [12][1280][160], W2 -> bf16 [12][80][1280]; one u32 (2 bf16) per thread.
__global__ __launch_bounds__(256) void prep_kernel(P p, u32* wp1o, u32* wp2o) {
    constexpr u32 N1 = 12u * 1280 * 80;   // u32 pairs of WP1
    constexpr u32 N2 = 12u * 80 * 640;    // u32 pairs of WP2
    u32 i = blockIdx.x * 256 + threadIdx.x;
    if (i < N1) {
        u32 j2 = i % 80, rem = i / 80;
        u32 k = rem % 1280, d = rem / 1280;
        u32 j0 = 2 * j2;
        const float* s = (j0 < 80) ? (p.iw1 + ((size_t)(d * 1280) + k) * 80 + j0)
                                   : (p.tw1 + ((size_t)(d * 1280) + k) * 80 + (j0 - 80));
        float2 v = *reinterpret_cast<const float2*>(s);
        wp1o[i] = (u32)f2bf(v.x) | ((u32)f2bf(v.y) << 16);
    } else {
        u32 ii = i - N1;
        if (ii >= N2) return;
        u32 c2 = ii % 640, rem = ii / 640;
        u32 k = rem % 80, d = rem / 80;
        u32 c0 = 2 * c2;
        const float* s = (c0 < 768) ? (p.iw2 + ((size_t)(d * 80) + k) * 768 + c0)
                                    : (p.tw2 + ((size_t)(d * 80) + k) * 512 + (c0 - 768));
        float2 v = *reinterpret_cast<const float2*>(s);
        wp2o[ii] = (u32)f2bf(v.x) | ((u32)f2bf(v.y) << 16);
    }
}

// Blocks 0..35: one (variant, token) row, all 12 depths, no inter-block sync.
// Blocks 36..71: common-prompt MLPs.
template <int PACKED>
__global__ __launch_bounds__(TPB) void chain_kernel(P p) {
    __shared__ float smem[6592];
    float* sx   = smem;           // [1280]
    float* xln0 = smem + 1280;    // [1280] img-LN
    float* xln1 = smem + 2560;    // [1280] txt-LN
    float* part = smem + 3840;    // [16][160]
    float* hh   = smem + 6400;    // [160]
    float* redA = smem + 6560;    // [10]
    float* redB = smem + 6570;    // [10]
    float* st   = smem + 6580;    // [2]

    const int tid = threadIdx.x;
    const int blk = blockIdx.x;

    if (blk < 36) {
        const int v = blk / 12, t = blk % 12;
        const float* is = (v == 2) ? p.vpm : p.vpc;   // [12][768]
        const float* ts = (v == 1) ? p.tpm : p.tpc;   // [12][512]
        if (tid < 512) { sx[768 + tid] = ts[t * 512 + tid]; }
        for (int k = tid; k < 768; k += TPB) sx[k] = is[t * 768 + k];
        __syncthreads();

        for (int d = 0; d < 12; ++d) {
            // ---- LN stats ----
            {
                float x0 = sx[tid], x1 = sx[tid + 640];
                float s = x0 + x1, s2 = x0 * x0 + x1 * x1;
                #pragma unroll
                for (int off = 32; off > 0; off >>= 1) { s += __shfl_down(s, off); s2 += __shfl_down(s2, off); }
                if ((tid & 63) == 0) { redA[tid >> 6] = s; redB[tid >> 6] = s2; }
            }
            __syncthreads();
            if (tid == 0) {
                float S = 0.f, S2 = 0.f;
                #pragma unroll
                for (int w = 0; w < 10; ++w) { S += redA[w]; S2 += redB[w]; }
                float m = S * (1.0f / 1280.0f);
                float var = S2 * (1.0f / 1280.0f) - m * m;
                st[0] = m; st[1] = rsqrtf(var + 1e-5f);
            }
            __syncthreads();
            const float m = st[0], rs = st[1];
            #pragma unroll
            for (int q = 0; q < 2; ++q) {
                const int k = tid + 640 * q;
                float xc = (sx[k] - m) * rs;
                xln0[k] = xc * p.lig[d * 1280 + k] + p.lib[d * 1280 + k];
                xln1[k] = xc * p.ltg[d * 1280 + k] + p.ltb[d * 1280 + k];
            }
            __syncthreads();
            // ---- GEMV1: 1280 -> 160 (both paths), 4 cols x K-chunk-80 per thread ----
            {
                const int g = tid % 40, kc = tid / 40;   // 16 chunks
                const int j0 = 4 * g;                    // col in [0,160)
                const float* xl = (j0 >= 80) ? xln1 : xln0;
                const int k0 = kc * 80;
                float a0 = 0.f, a1 = 0.f, a2 = 0.f, a3 = 0.f;
                if (PACKED) {
                    const u16* wp = p.wp1 + ((size_t)(d * 1280) + k0) * 160 + j0;
                    #pragma unroll 16
                    for (int i = 0; i < 80; ++i) {
                        uint2 w = *reinterpret_cast<const uint2*>(wp);
                        float xv = xl[k0 + i];
                        a0 += xv * bflo(w.x); a1 += xv * bfhi(w.x);
                        a2 += xv * bflo(w.y); a3 += xv * bfhi(w.y);
                        wp += 160;
                    }
                } else {
                    const float* wp = (j0 < 80) ? (p.iw1 + ((size_t)(d * 1280) + k0) * 80 + j0)
                                                : (p.tw1 + ((size_t)(d * 1280) + k0) * 80 + (j0 - 80));
                    #pragma unroll 8
                    for (int i = 0; i < 80; ++i) {
                        float4 w = *reinterpret_cast<const float4*>(wp);
                        float xv = xl[k0 + i];
                        a0 += xv * w.x; a1 += xv * w.y; a2 += xv * w.z; a3 += xv * w.w;
                        wp += 80;
                    }
                }
                *reinterpret_cast<float4*>(part + kc * 160 + j0) = make_float4(a0, a1, a2, a3);
            }
            __syncthreads();
            if (tid < 160) {
                const int path = tid >= 80, j = tid - 80 * path;
                float a = (path ? p.tb1 : p.ib1)[d * 80 + j];
                #pragma unroll
                for (int kc = 0; kc < 16; ++kc) a += part[kc * 160 + tid];
                hh[tid] = gelu_f(a);
            }
            __syncthreads();
            // ---- GEMV2: 80 -> 1280 (both paths), 2 cols full-K per thread ----
            {
                const int c = tid;
                const int pth = (c >= 384);
                const int cc = 2 * c - 768 * pth;
                const float* hb = hh + 80 * pth;
                float a0, a1;
                {
                    const float* b2 = (pth ? p.tb2 : p.ib2) + d * (pth ? 512 : 768) + cc;
                    a0 = b2[0]; a1 = b2[1];
                }
                if (PACKED) {
                    const u16* wp = p.wp2 + (size_t)(d * 80) * 1280 + 2 * c;
                    #pragma unroll 16
                    for (int k = 0; k < 80; ++k) {
                        u32 w = *reinterpret_cast<const u32*>(wp);
                        float hv = hb[k];
                        a0 += hv * bflo(w); a1 += hv * bfhi(w);
                        wp += 1280;
                    }
                } else {
                    const int Np = pth ? 512 : 768;
                    const float* wp = (pth ? p.tw2 + (size_t)(d * 80) * 512 : p.iw2 + (size_t)(d * 80) * 768) + cc;
                    #pragma unroll 16
                    for (int k = 0; k < 80; ++k) {
                        float2 w = *reinterpret_cast<const float2*>(wp);
                        float hv = hb[k];
                        a0 += hv * w.x; a1 += hv * w.y;
                        wp += Np;
                    }
                }
                sx[2 * c] = a0; sx[2 * c + 1] = a1;
                float* xo = pth ? (p.xt + ((size_t)(d * 36) + blk) * 512 + cc)
                                : (p.xi + ((size_t)(d * 36) + blk) * 768 + cc);
                *reinterpret_cast<float2*>(xo) = make_float2(a0, a1);
            }
            __syncthreads();
        }
    } else {
        // ---- common-prompt MLPs ----
        float* cx  = smem;         // [512]
        float* ph  = smem + 512;   // [4][64]
        float* hhl = smem + 768;   // [64]
        const int rr = blk - 36, v = rr / 12, t = rr % 12;
        const float* cs = (v == 0) ? p.cpc : (v == 1) ? p.cpi : p.cpt;
        if (tid < 512) cx[tid] = cs[t * 512 + tid];
        __syncthreads();
        if (tid < 256) {
            const int o = tid & 63, kc = tid >> 6;        // 4 K-chunks of 128
            const int path = o >> 5, j = o & 31;
            const float* w = (path ? p.ctw1 : p.ciw1) + (size_t)(kc * 128) * 32 + j;
            float a = 0.f;
            #pragma unroll 8
            for (int i = 0; i < 128; ++i) { a += cx[kc * 128 + i] * (*w); w += 32; }
            ph[kc * 64 + o] = a;
        }
        __syncthreads();
        if (tid < 64) {
            const int path = tid >> 5, j = tid & 31;
            float a = (path ? p.ctb1 : p.cib1)[j];
            #pragma unroll
            for (int kc = 0; kc < 4; ++kc) a += ph[kc * 64 + tid];
            hhl[tid] = gelu_f(a);
        }
        __syncthreads();
        for (int o = tid; o < 1280; o += TPB) {
            if (o < 768) {
                float a = p.cib2[o];
                #pragma unroll
                for (int k = 0; k < 32; ++k) a += hhl[k] * p.ciw2[k * 768 + o];
                p.cimg[rr * 768 + o] = a;
            } else {
                const int oo = o - 768;
                float a = p.ctb2[oo];
                #pragma unroll
                for (int k = 0; k < 32; ++k) a += hhl[32 + k] * p.ctw2[k * 512 + oo];
                p.ctxt[rr * 512 + oo] = a;
            }
        }
    }
}

// Broadcast/gather to the big f32 outputs, 4 elems (16 B) per thread-iteration.
__global__ __launch_bounds__(256) void emit_kernel(const int* __restrict__ mt,
                                                   const float* __restrict__ xi,
                                                   const float* __restrict__ xt,
                                                   const float* __restrict__ cimg,
                                                   const float* __restrict__ ctxt,
                                                   float* __restrict__ out) {
    constexpr unsigned int C0 = 512u * 24 * 192;       // img0  [512][24][768] /4
    constexpr unsigned int C1 = 512u * 24 * 128;       // txt0  [512][24][512] /4
    constexpr unsigned int C2 = 11u * 512 * 12 * 192;  // imgs  [11][512][12][768] /4
    constexpr unsigned int C3 = 11u * 512 * 12 * 128;  // txts  [11][512][12][512] /4
    constexpr unsigned int TOT = C0 + C1 + C2 + C3;
    const unsigned int stride = gridDim.x * blockDim.x;
    for (unsigned int c = blockIdx.x * blockDim.x + threadIdx.x; c < TOT; c += stride) {
        const float* src;
        if (c < C0) {
            unsigned int b = c / 4608u, r = c % 4608u;          // 24*192
            unsigned int tok = r / 192u, col = (r % 192u) * 4u;
            int v = mt[b];
            src = (tok < 12u) ? xi + ((size_t)v * 12 + tok) * 768 + col
                              : cimg + ((size_t)v * 12 + (tok - 12u)) * 768 + col;
        } else if (c < C0 + C1) {
            unsigned int cc = c - C0;
            unsigned int b = cc / 3072u, r = cc % 3072u;        // 24*128
            unsigned int tok = r / 128u, col = (r % 128u) * 4u;
            int v = mt[b];
            src = (tok < 12u) ? xt + ((size_t)v * 12 + tok) * 512 + col
                              : ctxt + ((size_t)v * 12 + (tok - 12u)) * 512 + col;
        } else if (c < C0 + C1 + C2) {
            unsigned int cc = c - C0 - C1;
            unsigned int d = cc / 1179648u, r = cc % 1179648u;  // 512*12*192
            unsigned int b = r / 2304u, rr = r % 2304u;         // 12*192
            unsigned int tok = rr / 192u, col = (rr % 192u) * 4u;
            int v = mt[b];
            src = xi + ((size_t)(d + 1) * 36 + v * 12 + tok) * 768 + col;
        } else {
            unsigned int cc = c - C0 - C1 - C2;
            unsigned int d = cc / 786432u, r = cc % 786432u;    // 512*12*128
            unsigned int b = r / 1536u, rr = r % 1536u;         // 12*128
            unsigned int tok = rr / 128u, col = (rr % 128u) * 4u;
            int v = mt[b];
            src = xt + ((size_t)(d + 1) * 36 + v * 12 + tok) * 512 + col;
        }
        *reinterpret_cast<float4*>(out + (size_t)c * 4) = *reinterpret_cast<const float4*>(src);
    }
}

extern "C" void kernel_launch(void* const* d_in, const int* in_sizes, int n_in,
                              void* d_out, int out_size, void* d_ws, size_t ws_size,
                              hipStream_t stream) {
    const int* mt = (const int*)d_in[0];
    float* ws = (float*)d_ws;
    P p;
    p.vpc  = (const float*)d_in[1];
    p.vpm  = (const float*)d_in[2];
    p.tpc  = (const float*)d_in[3];
    p.tpm  = (const float*)d_in[4];
    p.cpc  = (const float*)d_in[5];
    p.cpi  = (const float*)d_in[6];
    p.cpt  = (const float*)d_in[7];
    p.lig  = (const float*)d_in[8];
    p.lib  = (const float*)d_in[9];
    p.ltg  = (const float*)d_in[10];
    p.ltb  = (const float*)d_in[11];
    p.iw1  = (const float*)d_in[12];
    p.ib1  = (const float*)d_in[13];
    p.iw2  = (const float*)d_in[14];
    p.ib2  = (const float*)d_in[15];
    p.tw1  = (const float*)d_in[16];
    p.tb1  = (const float*)d_in[17];
    p.tw2  = (const float*)d_in[18];
    p.tb2  = (const float*)d_in[19];
    p.ciw1 = (const float*)d_in[20];
    p.cib1 = (const float*)d_in[21];
    p.ciw2 = (const float*)d_in[22];
    p.cib2 = (const float*)d_in[23];
    p.ctw1 = (const float*)d_in[24];
    p.ctb1 = (const float*)d_in[25];
    p.ctw2 = (const float*)d_in[26];
    p.ctb2 = (const float*)d_in[27];

    const bool packed = (ws_size >= F_END_P * sizeof(float));
    if (packed) {
        p.wp1  = (const u16*)(ws + F_WP1);
        p.wp2  = (const u16*)(ws + F_WP2);
        p.xi   = ws + F_XI_P;
        p.xt   = ws + F_XT_P;
        p.cimg = ws + F_CI_P;
        p.ctxt = ws + F_CT_P;
        constexpr u32 NPAIR = 12u * 1280 * 80 + 12u * 80 * 640;   // 1,843,200
        prep_kernel<<<dim3((NPAIR + 255) / 256), dim3(256), 0, stream>>>(p, (u32*)(ws + F_WP1), (u32*)(ws + F_WP2));
        chain_kernel<1><<<dim3(72), dim3(TPB), 0, stream>>>(p);
    } else {
        p.wp1 = nullptr; p.wp2 = nullptr;
        p.xi   = ws + F_XI_U;
        p.xt   = ws + F_XT_U;
        p.cimg = ws + F_CI_U;
        p.ctxt = ws + F_CT_U;
        chain_kernel<0><<<dim3(72), dim3(TPB), 0, stream>>>(p);
    }
    emit_kernel<<<dim3(4096), dim3(256), 0, stream>>>(mt, p.xi, p.xt, p.cimg, p.ctxt, (float*)d_out);
}